// Round 1
// baseline (303.013 us; speedup 1.0000x reference)
//
#include <hip/hip_runtime.h>
#include <cstdint>

// CRF loss forward, B=4096 T=512 L=16.
// One batch per wave64. lane l: j = l>>2 (output label), g = l&3 (input-label quad).
// Base-2 log space; renormalize by u[0] via readfirstlane each step (no max tree).
// x/labels double-buffered in LDS via global_load_lds, 64-step chunks, vmcnt(5) counted wait.

static constexpr float L2E = 1.4426950408889634f;   // log2(e)
static constexpr float LN2 = 0.69314718055994531f;  // ln(2)

__device__ __forceinline__ void gload_lds16(const void* g, void* l) {
  __builtin_amdgcn_global_load_lds((const __attribute__((address_space(1))) unsigned int*)g,
                                   (__attribute__((address_space(3))) unsigned int*)l, 16, 0, 0);
}
__device__ __forceinline__ void gload_lds4(const void* g, void* l) {
  __builtin_amdgcn_global_load_lds((const __attribute__((address_space(1))) unsigned int*)g,
                                   (__attribute__((address_space(3))) unsigned int*)l, 4, 0, 0);
}
__device__ __forceinline__ void wait_vm0() { asm volatile("s_waitcnt vmcnt(0)" ::: "memory"); }
__device__ __forceinline__ void wait_vm5() { asm volatile("s_waitcnt vmcnt(5)" ::: "memory"); }

// quad_perm DPP add: v += v[lane ^ m] within each 4-lane quad
template <int CTRL>
__device__ __forceinline__ float qadd(float v) {
  int x = __builtin_amdgcn_mov_dpp(__builtin_bit_cast(int, v), CTRL, 0xF, 0xF, true);
  return v + __builtin_bit_cast(float, x);
}

__global__ __launch_bounds__(256, 4) void crf_fwd(
    const float* __restrict__ x, const float* __restrict__ trans,
    const int* __restrict__ label, const int* __restrict__ length,
    float* __restrict__ out) {
  __shared__ float ldsx[4][2][64 * 16];  // per-wave, double-buffered, 64 timesteps x 16 labels
  __shared__ int   ldsl[4][2][64];       // labels per chunk
  __shared__ float ldst[256];            // natural-log trans table (block-shared)

  const int tid  = threadIdx.x;
  const int wv   = tid >> 6;
  const int lane = tid & 63;
  const int j    = lane >> 2;  // output label
  const int g    = lane & 3;   // input-label quad index

  ldst[tid] = trans[tid];  // blockDim == 256 == L*L
  __syncthreads();

  const int b   = blockIdx.x * 4 + wv;
  const int len = length[b];
  const int nch = ((len - 1) >> 6) + 1;  // chunks of 64 timesteps needed

  // per-lane trans columns (base-2 scaled): tc_k = log2e * trans[(4g+k)][j]
  const float tc0 = trans[(4 * g + 0) * 16 + j] * L2E;
  const float tc1 = trans[(4 * g + 1) * 16 + j] * L2E;
  const float tc2 = trans[(4 * g + 2) * 16 + j] * L2E;
  const float tc3 = trans[(4 * g + 3) * 16 + j] * L2E;

  // bpermute byte addresses: u[i] lives at lane 4*i; i = 4g+k  ->  byte 4*(16g+4k)
  const int a0 = (16 * g + 0) * 4;
  const int a1 = (16 * g + 4) * 4;
  const int a2 = (16 * g + 8) * 4;
  const int a3 = (16 * g + 12) * 4;

  const char* xb = (const char*)x + (size_t)b * 32768;      // 512*16*4
  const char* lb = (const char*)label + (size_t)b * 2048;   // 512*4

  auto stage = [&](int c, int buf) {
    const char* gx = xb + c * 4096;
    float* lx = &ldsx[wv][buf][0];
    gload_lds16(gx + 0 * 1024 + lane * 16, lx + 0 * 256);
    gload_lds16(gx + 1 * 1024 + lane * 16, lx + 1 * 256);
    gload_lds16(gx + 2 * 1024 + lane * 16, lx + 2 * 256);
    gload_lds16(gx + 3 * 1024 + lane * 16, lx + 3 * 256);
    gload_lds4(lb + c * 256 + lane * 4, &ldsl[wv][buf][0]);
  };

  stage(0, 0);

  float u = 0.0f;   // alpha2[j] - R (replicated across each quad)
  float R = 0.0f;   // accumulated base-2 renormalization
  float em = 0.0f;  // natural-log emission score
  float ts = 0.0f;  // natural-log transition score
  int lp = 0;       // previous label
  int t = 1;

  for (int c = 0; c < nch; ++c) {
    const int buf = c & 1;
    const bool pre = (c + 1 < nch);
    if (pre) stage(c + 1, buf ^ 1);
    if (pre) wait_vm5(); else wait_vm0();  // chunk c's 5 loads complete (in-order vmcnt)

    float* lx = &ldsx[wv][buf][0];
    int*   ll = &ldsl[wv][buf][0];

    if (c == 0) {
      u  = lx[j] * L2E;   // alpha2_0 = x2[0][:]
      lp = ll[0];
      em = lx[lp];        // emit at t=0 (natural units)
    }

    const int tend = (len - 1 < c * 64 + 63) ? (len - 1) : (c * 64 + 63);
    for (; t <= tend; ++t) {
      const int idx = t & 63;
      const float C = __builtin_bit_cast(
          float, __builtin_amdgcn_readfirstlane(__builtin_bit_cast(int, u)));  // u[0]
      const int ui = __builtin_bit_cast(int, u);
      const float g0 = __builtin_bit_cast(float, __builtin_amdgcn_ds_bpermute(a0, ui));
      const float g1 = __builtin_bit_cast(float, __builtin_amdgcn_ds_bpermute(a1, ui));
      const float g2 = __builtin_bit_cast(float, __builtin_amdgcn_ds_bpermute(a2, ui));
      const float g3 = __builtin_bit_cast(float, __builtin_amdgcn_ds_bpermute(a3, ui));
      const float e0 = __builtin_amdgcn_exp2f(g0 + (tc0 - C));
      const float e1 = __builtin_amdgcn_exp2f(g1 + (tc1 - C));
      const float e2 = __builtin_amdgcn_exp2f(g2 + (tc2 - C));
      const float e3 = __builtin_amdgcn_exp2f(g3 + (tc3 - C));
      float s = (e0 + e1) + (e2 + e3);
      s = qadd<0xB1>(s);  // quad_perm [1,0,3,2] : xor 1
      s = qadd<0x4E>(s);  // quad_perm [2,3,0,1] : xor 2
      const float xr = lx[idx * 16 + j];
      u = __builtin_fmaf(xr, L2E, __builtin_amdgcn_logf(s));
      R += C;
      // scores (uniform across wave; broadcast LDS reads)
      const int lbl = ll[idx];
      em += lx[idx * 16 + lbl];
      ts += ldst[lp * 16 + lbl];
      lp = lbl;
    }
  }

  // z = R + log2( sum_j 2^u[j] ); each u[j] appears 4x in the wave -> subtract log2(4)
  float stot = __builtin_amdgcn_exp2f(u);
  stot += __shfl_xor(stot, 1, 64);
  stot += __shfl_xor(stot, 2, 64);
  stot += __shfl_xor(stot, 4, 64);
  stot += __shfl_xor(stot, 8, 64);
  stot += __shfl_xor(stot, 16, 64);
  stot += __shfl_xor(stot, 32, 64);
  const float z2 = R + __builtin_amdgcn_logf(stot) - 2.0f;
  const float res = z2 * LN2 - em - ts;
  if (lane == 0) out[b] = res;
}

extern "C" void kernel_launch(void* const* d_in, const int* in_sizes, int n_in,
                              void* d_out, int out_size, void* d_ws, size_t ws_size,
                              hipStream_t stream) {
  const float* x      = (const float*)d_in[0];
  const float* trans  = (const float*)d_in[1];
  const int*   label  = (const int*)d_in[2];
  const int*   length = (const int*)d_in[3];
  float* out = (float*)d_out;
  const int B = in_sizes[3];  // 4096
  crf_fwd<<<dim3(B / 4), dim3(256), 0, stream>>>(x, trans, label, length, out);
}

// Round 2
// 251.482 us; speedup vs baseline: 1.2049x; 1.2049x over previous
//
#include <hip/hip_runtime.h>
#include <cstdint>

// CRF loss forward, B=4096 T=512 L=16 — linear-space recursion.
// One batch per wave64. lane l: j = l>>2 (output label), g = l&3 (input quad).
// a'_j = (sum_i a_i * M_ij) * exp(x_t_j),  M = exp(trans), renorm by a_0 every 4 steps.
// x staged via global_load_lds (64-step chunks, double-buffered, vmcnt(5) counted wait),
// then exp-transformed in place; em/ts scores computed per-chunk in parallel (lane = t).

static constexpr float L2E = 1.4426950408889634f;   // log2(e)
static constexpr float LN2 = 0.69314718055994531f;  // ln(2)

__device__ __forceinline__ void gload_lds16(const void* g, void* l) {
  __builtin_amdgcn_global_load_lds((const __attribute__((address_space(1))) unsigned int*)g,
                                   (__attribute__((address_space(3))) unsigned int*)l, 16, 0, 0);
}
__device__ __forceinline__ void gload_lds4(const void* g, void* l) {
  __builtin_amdgcn_global_load_lds((const __attribute__((address_space(1))) unsigned int*)g,
                                   (__attribute__((address_space(3))) unsigned int*)l, 4, 0, 0);
}
__device__ __forceinline__ void wait_vm0() { asm volatile("s_waitcnt vmcnt(0)" ::: "memory"); }
__device__ __forceinline__ void wait_vm5() { asm volatile("s_waitcnt vmcnt(5)" ::: "memory"); }

// quad_perm DPP add: v += v[lane ^ m] within each 4-lane quad
template <int CTRL>
__device__ __forceinline__ float qadd(float v) {
  int x = __builtin_amdgcn_mov_dpp(__builtin_bit_cast(int, v), CTRL, 0xF, 0xF, true);
  return v + __builtin_bit_cast(float, x);
}
__device__ __forceinline__ float rfl(float v) {
  return __builtin_bit_cast(float, __builtin_amdgcn_readfirstlane(__builtin_bit_cast(int, v)));
}

__global__ __launch_bounds__(256, 4) void crf_fwd(
    const float* __restrict__ x, const float* __restrict__ trans,
    const int* __restrict__ label, const int* __restrict__ length,
    float* __restrict__ out) {
  __shared__ float ldsx[4][2][64 * 16];  // per-wave, double-buffered, 64 timesteps x 16 labels
  __shared__ int   ldsl[4][2][64];       // labels per chunk
  __shared__ float ldst[256];            // raw trans table (natural log units)

  const int tid  = threadIdx.x;
  const int wv   = tid >> 6;
  const int lane = tid & 63;
  const int j    = lane >> 2;  // output label
  const int g    = lane & 3;   // input-label quad index

  ldst[tid] = trans[tid];  // blockDim == 256 == L*L
  __syncthreads();

  const int b   = blockIdx.x * 4 + wv;
  const int len = length[b];
  const int nch = ((len - 1) >> 6) + 1;  // chunks of 64 timesteps needed

  // M columns: m_k = exp(trans[4g+k][j])
  const float m0 = __builtin_amdgcn_exp2f(trans[(4 * g + 0) * 16 + j] * L2E);
  const float m1 = __builtin_amdgcn_exp2f(trans[(4 * g + 1) * 16 + j] * L2E);
  const float m2 = __builtin_amdgcn_exp2f(trans[(4 * g + 2) * 16 + j] * L2E);
  const float m3 = __builtin_amdgcn_exp2f(trans[(4 * g + 3) * 16 + j] * L2E);

  // bpermute byte addresses: a_i lives at lane 4*i; i = 4g+k  ->  byte 4*(16g+4k)
  const int a0 = (16 * g + 0) * 4;
  const int a1 = (16 * g + 4) * 4;
  const int a2 = (16 * g + 8) * 4;
  const int a3 = (16 * g + 12) * 4;

  const char* xb = (const char*)x + (size_t)b * 32768;      // 512*16*4
  const char* lb = (const char*)label + (size_t)b * 2048;   // 512*4

  auto stage = [&](int c, int buf) {
    const char* gx = xb + c * 4096;
    float* lxp = &ldsx[wv][buf][0];
    gload_lds16(gx + 0 * 1024 + lane * 16, lxp + 0 * 256);
    gload_lds16(gx + 1 * 1024 + lane * 16, lxp + 1 * 256);
    gload_lds16(gx + 2 * 1024 + lane * 16, lxp + 2 * 256);
    gload_lds16(gx + 3 * 1024 + lane * 16, lxp + 3 * 256);
    gload_lds4(lb + c * 256 + lane * 4, &ldsl[wv][buf][0]);
  };

  stage(0, 0);

  float av = 1.0f;  // linear-space alpha_j / 2^R2 (replicated across each quad)
  float R2 = 0.0f;  // accumulated base-2 renormalization
  float em = 0.0f;  // emission score (natural units)
  float ts = 0.0f;  // transition score (natural units)
  int lastl = 0;    // label at last timestep of previous chunk

  for (int c = 0; c < nch; ++c) {
    const int buf = c & 1;
    const bool pre = (c + 1 < nch);
    if (pre) stage(c + 1, buf ^ 1);
    if (pre) wait_vm5(); else wait_vm0();  // chunk c's 5 loads complete (in-order vmcnt)

    float* lx = &ldsx[wv][buf][0];
    int*   ll = &ldsl[wv][buf][0];

    // ---- parallel em/ts pass: lane handles timestep c*64+lane ----
    {
      const int gt   = c * 64 + lane;
      const int lblt = ll[lane];
      const int lprv = (lane == 0) ? lastl : ll[lane - 1];
      const float emv = lx[lane * 16 + lblt];
      const float tsv = ldst[lprv * 16 + lblt];
      if (gt < len) em += emv;
      if (gt >= 1 && gt < len) ts += tsv;
      lastl = __shfl(lblt, 63, 64);
    }

    // ---- in-place transform: x -> exp(x); lane owns floats [lane*16, lane*16+16) ----
    {
      float4* p = (float4*)(lx + lane * 16);
#pragma unroll
      for (int k = 0; k < 4; ++k) {
        float4 v = p[k];
        v.x = __builtin_amdgcn_exp2f(v.x * L2E);
        v.y = __builtin_amdgcn_exp2f(v.y * L2E);
        v.z = __builtin_amdgcn_exp2f(v.z * L2E);
        v.w = __builtin_amdgcn_exp2f(v.w * L2E);
        p[k] = v;
      }
    }

    if (c == 0) av = lx[j];  // a_0 = exp(x[0][:])

    const int start = (c == 0) ? 1 : c * 64;
    const int end   = (len - 1 < c * 64 + 63) ? (len - 1) : (c * 64 + 63);
    const int n     = end - start + 1;
    if (n > 0) {
      const float* exp_ = lx + (start & 63) * 16 + j;

      auto step = [&]() {
        const int ai = __builtin_bit_cast(int, av);
        const float g0 = __builtin_bit_cast(float, __builtin_amdgcn_ds_bpermute(a0, ai));
        const float g1 = __builtin_bit_cast(float, __builtin_amdgcn_ds_bpermute(a1, ai));
        const float g2 = __builtin_bit_cast(float, __builtin_amdgcn_ds_bpermute(a2, ai));
        const float g3 = __builtin_bit_cast(float, __builtin_amdgcn_ds_bpermute(a3, ai));
        float v01 = __builtin_fmaf(g1, m1, g0 * m0);
        float v23 = __builtin_fmaf(g3, m3, g2 * m2);
        float v = v01 + v23;
        v = qadd<0xB1>(v);  // quad_perm [1,0,3,2] : xor 1
        v = qadd<0x4E>(v);  // quad_perm [2,3,0,1] : xor 2
        av = v * (*exp_);
        exp_ += 16;
      };

      const int n4 = n >> 2, rem = n & 3;
      for (int q = 0; q < n4; ++q) {
        step(); step(); step(); step();
        // renorm every 4 steps (range-safe for >=7 steps worst case)
        const float Cs = rfl(av);
        const float rs = __builtin_amdgcn_rcpf(Cs);
        av *= rs;
        R2 += __builtin_amdgcn_logf(Cs);  // log2
      }
      for (int e = 0; e < rem; ++e) step();
    }
  }

  // z = (R2 + log2(sum_j a_j)) * ln2 ; each a_j appears 4x in the wave -> -log2(4)
  float stot = av;
  stot += __shfl_xor(stot, 1, 64);
  stot += __shfl_xor(stot, 2, 64);
  stot += __shfl_xor(stot, 4, 64);
  stot += __shfl_xor(stot, 8, 64);
  stot += __shfl_xor(stot, 16, 64);
  stot += __shfl_xor(stot, 32, 64);

  em += __shfl_xor(em, 1, 64);
  em += __shfl_xor(em, 2, 64);
  em += __shfl_xor(em, 4, 64);
  em += __shfl_xor(em, 8, 64);
  em += __shfl_xor(em, 16, 64);
  em += __shfl_xor(em, 32, 64);

  ts += __shfl_xor(ts, 1, 64);
  ts += __shfl_xor(ts, 2, 64);
  ts += __shfl_xor(ts, 4, 64);
  ts += __shfl_xor(ts, 8, 64);
  ts += __shfl_xor(ts, 16, 64);
  ts += __shfl_xor(ts, 32, 64);

  const float z2 = R2 + __builtin_amdgcn_logf(stot) - 2.0f;
  const float res = z2 * LN2 - em - ts;
  if (lane == 0) out[b] = res;
}

extern "C" void kernel_launch(void* const* d_in, const int* in_sizes, int n_in,
                              void* d_out, int out_size, void* d_ws, size_t ws_size,
                              hipStream_t stream) {
  const float* x      = (const float*)d_in[0];
  const float* trans  = (const float*)d_in[1];
  const int*   label  = (const int*)d_in[2];
  const int*   length = (const int*)d_in[3];
  float* out = (float*)d_out;
  const int B = in_sizes[3];  // 4096
  crf_fwd<<<dim3(B / 4), dim3(256), 0, stream>>>(x, trans, label, length, out);
}